// Round 14
// baseline (246.923 us; speedup 1.0000x reference)
//
#include <hip/hip_runtime.h>
#include <hip/hip_bf16.h>
#include <math.h>

// HashMemory: B=8, S=4096, E=1024, Dm=512, M=64 slots.
// memory at step t == write_vals of tokens [t-64, t-1]  => window-64 attention.
// Pipeline: prep; WVQ = embb @ [W_write|W_query] (256^2 MFMA GEMM, epilogue
// also emits WVT); attention (MFMA QK^T + wave-local softmax + MFMA PV);
// out = R @ W_out.
// r14: GEMM -> BK=32, LDS 64KB (2buf x (A16K|B16K)) => 2 BLOCKS/CU.
// Diagnosis: r8-r13 all 1 block/CU (128KB LDS) -> 8 waves lockstep on
// barriers, Occupancy 18%. Schedule variants null because no co-resident
// block existed to cover drains. 2 blocks/CU provides the overlap.
// Per tile: stage 4 regions, B-frags x4 in regs, A-frags x8, 32 MFMA/wave.

#define BATCH   8
#define S_LEN   4096
#define EMB     1024
#define DM      512
#define MROWS   (BATCH * S_LEN)          // 32768
#define SCALE_F 0.04419417382415922f     // 512^-0.5

typedef __attribute__((ext_vector_type(4))) float f32x4;
typedef __attribute__((ext_vector_type(8))) short short8;

__device__ __forceinline__ unsigned short f2bf(float f) {
    __hip_bfloat16 h = __float2bfloat16(f);
    return *reinterpret_cast<unsigned short*>(&h);
}

// ---------------------------------------------------------------------------
// Fused prep: emb f32->bf16 cast (blocks 0..32767), W_wr/W_qr/W_out
// transpose+cast (blocks 32768..38911), bias concat (block 38912).
// ---------------------------------------------------------------------------
__global__ __launch_bounds__(256) void prep(
    const float4* __restrict__ emb4, ushort4* __restrict__ embb4,
    const float* __restrict__ W_wr, const float* __restrict__ W_qr,
    const float* __restrict__ W_out,
    const float* __restrict__ b_wr, const float* __restrict__ b_qr,
    __hip_bfloat16* __restrict__ wcat, __hip_bfloat16* __restrict__ wout,
    float* __restrict__ bcat)
{
    const int bx = blockIdx.x;
    if (bx < 32768) {                              // emb cast: 8M float4
        int id = bx * 256 + threadIdx.x;
        float4 v = emb4[id];
        ushort4 o;
        o.x = f2bf(v.x); o.y = f2bf(v.y); o.z = f2bf(v.z); o.w = f2bf(v.w);
        embb4[id] = o;
    } else if (bx < 32768 + 2048) {                // wcat[0:512][1024] = W_wr^T
        int id = (bx - 32768) * 256 + threadIdx.x;
        int n = id >> 10, k = id & 1023;
        wcat[id] = __float2bfloat16(W_wr[k * 512 + n]);
    } else if (bx < 32768 + 4096) {                // wcat[512:1024][1024] = W_qr^T
        int id = (bx - 32768 - 2048) * 256 + threadIdx.x;
        int n = id >> 10, k = id & 1023;
        wcat[(size_t)DM * EMB + id] = __float2bfloat16(W_qr[k * 512 + n]);
    } else if (bx < 32768 + 6144) {                // wout[1024][512] = W_out^T
        int id = (bx - 32768 - 4096) * 256 + threadIdx.x;
        int n = id >> 9, k = id & 511;
        wout[id] = __float2bfloat16(W_out[k * 1024 + n]);
    } else {                                       // bias concat
        int i = threadIdx.x;
#pragma unroll
        for (int r = 0; r < 4; ++r, i += 256)
            bcat[i] = (i < 512) ? b_wr[i] : b_qr[i - 512];
    }
}

// ---------------------------------------------------------------------------
// bf16 MFMA GEMM, 256x256 tile, BK=32, 8 waves (2x4), 2 blocks/CU.
// LDS: 2buf x (A 16K | B 16K) = 64KB. Rows 64B (32 bf16), 4 chunks/row,
// swizzle chunk ^= (row>>1)&3 (r7-verified), applied both sides.
// Region = 128 rows x 32 cols = 8KB = one gload_lds per thread.
// ---------------------------------------------------------------------------
template<bool BF16OUT, bool TRANSLO>
__global__ __launch_bounds__(512, 2) void gemm256(
    const __hip_bfloat16* __restrict__ A, int lda,
    const __hip_bfloat16* __restrict__ Bt, int ldb,
    const float* __restrict__ bias,
    void* __restrict__ Cv, int ldc,
    __hip_bfloat16* __restrict__ wvtp,
    int K, int nbx)
{
    __shared__ __align__(16) char smem[65536];

    const int nwg = gridDim.x;
    const int bid = blockIdx.x;
    const int cpx = nwg >> 3;                    // nwg divisible by 8
    const int swz = (bid & 7) * cpx + (bid >> 3);
    const int bm0 = (swz / nbx) << 8;
    const int bn0 = (swz % nbx) << 8;

    const int tid  = threadIdx.x;
    const int lane = tid & 63;
    const int w    = tid >> 6;                   // 0..7
    const int wm   = w >> 2, wn = w & 3;         // 2x4 wave grid
    const int l15  = lane & 15, lhi = lane >> 4; // lhi in 0..3
    const int nt   = K >> 5;

    // staging: thread owns linear LDS slot tid*16 per 8KB region =>
    // row-in-region = tid>>2 (0..127), phys chunk tid&3;
    // source chunk = (tid&3) ^ ((row>>1)&3).
    const int srow = tid >> 2;
    const int cg8  = ((tid & 3) ^ ((srow >> 1) & 3)) << 3;   // col in elems

    auto stage_tile = [&](int buf, int kt) {     // 4 gloads per thread
#pragma unroll
        for (int h = 0; h < 4; ++h) {            // 0=A0 1=A1 2=B0 3=B1
            const int isB = h >> 1, rg = h & 1;
            const __hip_bfloat16* G = isB ? Bt : A;
            const int ldg = isB ? ldb : lda;
            const int rb  = (isB ? bn0 : bm0) + rg * 128;
            const __hip_bfloat16* g =
                G + (size_t)(rb + srow) * ldg + kt + cg8;
            char* l = smem + buf * 32768 + isB * 16384 + rg * 8192
                      + w * 1024;                // wave-uniform; HW adds lane*16
            __builtin_amdgcn_global_load_lds(
                (const __attribute__((address_space(1))) unsigned int*)g,
                (__attribute__((address_space(3))) unsigned int*)l, 16, 0, 0);
        }
    };

    f32x4 acc[8][4] = {};   // [m-frag 0..7 (rows wm*128+m*16)][n-frag 0..3]

    stage_tile(0, 0);
    __syncthreads();

    for (int t = 0; t < nt; ++t) {
        const int cur = t & 1;
        const bool pf = (t + 1 < nt);
        if (pf) stage_tile(cur ^ 1, (t + 1) << 5);   // fly under compute

        const char* sA = smem + cur * 32768;
        const char* sB = sA + 16384;

        // ---- B fragments: 4 reads, held for the whole tile ----
        short8 bfv[4];
#pragma unroll
        for (int n4 = 0; n4 < 4; ++n4) {
            const int r  = wn * 64 + n4 * 16 + l15;      // 0..255
            const int pc = lhi ^ ((r >> 1) & 3);
            bfv[n4] = *(const short8*)(sB + (r >> 7) * 8192
                                          + (r & 127) * 64 + (pc << 4));
        }

        // ---- A fragments: 8 reads, 4 MFMA each ----
#pragma unroll
        for (int m8 = 0; m8 < 8; ++m8) {
            const int r  = wm * 128 + m8 * 16 + l15;     // 0..255
            const int pc = lhi ^ ((r >> 1) & 3);
            short8 af = *(const short8*)(sA + (r >> 7) * 8192
                                            + (r & 127) * 64 + (pc << 4));
#pragma unroll
            for (int n4 = 0; n4 < 4; ++n4)
                acc[m8][n4] = __builtin_amdgcn_mfma_f32_16x16x32_bf16(
                    af, bfv[n4], acc[m8][n4], 0, 0, 0);
        }

        if (pf) __syncthreads();   // other resident block covers the drain
    }

    // ---- epilogue (mapping identical to r12: M=m8, N=n4) ----
    float bv[4];
#pragma unroll
    for (int N = 0; N < 4; ++N)
        bv[N] = bias[bn0 + wn * 64 + N * 16 + l15];

#pragma unroll
    for (int M = 0; M < 8; ++M) {
        const int row = bm0 + wm * 128 + M * 16 + lhi * 4;
#pragma unroll
        for (int N = 0; N < 4; ++N) {
            const int col = bn0 + wn * 64 + N * 16 + l15;
            float v[4];
#pragma unroll
            for (int reg = 0; reg < 4; ++reg)
                v[reg] = acc[M][N][reg] + bv[N];

#pragma unroll
            for (int reg = 0; reg < 4; ++reg) {
                if (BF16OUT)
                    ((__hip_bfloat16*)Cv)[(size_t)(row + reg) * ldc + col] =
                        __float2bfloat16(v[reg]);
                else
                    ((float*)Cv)[(size_t)(row + reg) * ldc + col] = v[reg];
            }
            if (TRANSLO && col < 512) {
                union { unsigned short s[4]; uint2 u; } tv;
#pragma unroll
                for (int reg = 0; reg < 4; ++reg) tv.s[reg] = f2bf(v[reg]);
                *(uint2*)((unsigned short*)wvtp
                          + (((size_t)((row >> 12) * 512 + col)) << 12)
                          + (row & 4095)) = tv.u;
            }
        }
    }
}

// ---------------------------------------------------------------------------
// MFMA windowed attention. Block = 64 tokens, 4 waves, XCD-chunked swizzle.
// ---------------------------------------------------------------------------
__global__ __launch_bounds__(256) void attn_mfma(
    const __hip_bfloat16* __restrict__ WVQ,   // [32768][1024]: 0:512=WV, 512:=Q
    const __hip_bfloat16* __restrict__ WVT,   // [8][512][4096]
    __hip_bfloat16* __restrict__ R)           // [32768][512]
{
    __shared__ __align__(16) unsigned short p_lds[64][136];  // 17408 B

    const int blk0 = blockIdx.x;                 // 512 blocks, 512%8==0
    const int blk  = (blk0 & 7) * 64 + (blk0 >> 3);   // XCD-chunked (T1)
    const int b   = blk >> 6;
    const int t0  = (blk & 63) << 6;
    const int jmin = (t0 == 0) ? 64 : 0;
    const size_t bbase = (size_t)b << 12;
    const int tid  = threadIdx.x;
    const int lane = tid & 63;
    const int w    = tid >> 6;
    const int l15  = lane & 15;
    const int lhi  = lane >> 4;

    // ---- QK^T:  S[64][128] ----
    f32x4 acc[8] = {};
    const __hip_bfloat16* q0 =
        WVQ + ((bbase + t0 + w * 16 + l15) << 10) + 512 + lhi * 8;

    const __hip_bfloat16* brow[8];
#pragma unroll
    for (int nt = 0; nt < 8; ++nt) {
        int aj = t0 - 64 + nt * 16 + l15;
        if (aj < 0) aj = 0;                 // clamped; masked below
        brow[nt] = WVQ + ((bbase + aj) << 10) + lhi * 8;
    }

#pragma unroll 2
    for (int kt = 0; kt < 16; ++kt) {
        short8 qa = *(const short8*)(q0 + kt * 32);
#pragma unroll
        for (int nt = 0; nt < 8; ++nt) {
            short8 bv = *(const short8*)(brow[nt] + kt * 32);
            acc[nt] = __builtin_amdgcn_mfma_f32_16x16x32_bf16(qa, bv, acc[nt], 0, 0, 0);
        }
    }

    // ---- wave-local softmax ----
    float m4[4] = { -1e30f, -1e30f, -1e30f, -1e30f };
#pragma unroll
    for (int nt = 0; nt < 8; ++nt)
#pragma unroll
        for (int reg = 0; reg < 4; ++reg) {
            int i = w * 16 + lhi * 4 + reg;
            int j = nt * 16 + l15;
            bool valid = (j >= i) && (j <= i + 63) && (j >= jmin);
            float s = valid ? acc[nt][reg] * SCALE_F : -1e30f;
            acc[nt][reg] = s;
            m4[reg] = fmaxf(m4[reg], s);
        }
#pragma unroll
    for (int off = 8; off >= 1; off >>= 1)
#pragma unroll
        for (int reg = 0; reg < 4; ++reg)
            m4[reg] = fmaxf(m4[reg], __shfl_xor(m4[reg], off, 64));

    float sum4[4] = {};
#pragma unroll
    for (int nt = 0; nt < 8; ++nt)
#pragma unroll
        for (int reg = 0; reg < 4; ++reg) {
            float s = acc[nt][reg];
            float p = (s > -1e29f) ? __expf(s - m4[reg]) : 0.f;
            acc[nt][reg] = p;
            sum4[reg] += p;
        }
#pragma unroll
    for (int off = 8; off >= 1; off >>= 1)
#pragma unroll
        for (int reg = 0; reg < 4; ++reg)
            sum4[reg] += __shfl_xor(sum4[reg], off, 64);

    float rs4[4];
#pragma unroll
    for (int reg = 0; reg < 4; ++reg)
        rs4[reg] = (sum4[reg] > 0.f) ? 1.f / sum4[reg] : 0.f;

#pragma unroll
    for (int nt = 0; nt < 8; ++nt)
#pragma unroll
        for (int reg = 0; reg < 4; ++reg)
            p_lds[w * 16 + lhi * 4 + reg][nt * 16 + l15] =
                f2bf(acc[nt][reg] * rs4[reg]);

    __syncthreads();

    // ---- PV ----
    short8 pa[4];
#pragma unroll
    for (int kt = 0; kt < 4; ++kt)
        pa[kt] = *(const short8*)&p_lds[w * 16 + l15][kt * 32 + lhi * 8];

    int tclamp[4];
#pragma unroll
    for (int kt = 0; kt < 4; ++kt) {
        int ti = t0 - 64 + kt * 32 + lhi * 8;
        tclamp[kt] = ti < 0 ? 0 : ti;       // 8-chunks never straddle 0
    }

    const size_t vbase = (size_t)b * 512;
#pragma unroll 2
    for (int nt = 0; nt < 32; ++nt) {
        int d = nt * 16 + l15;
        f32x4 a = {};
#pragma unroll
        for (int kt = 0; kt < 4; ++kt) {
            short8 bv = *(const short8*)(WVT + ((vbase + d) << 12) + tclamp[kt]);
            a = __builtin_amdgcn_mfma_f32_16x16x32_bf16(pa[kt], bv, a, 0, 0, 0);
        }
        size_t rb = (bbase + t0 + w * 16 + lhi * 4) << 9;
#pragma unroll
        for (int reg = 0; reg < 4; ++reg)
            R[rb + ((size_t)reg << 9) + d] = __float2bfloat16(a[reg]);
    }
}

// ---------------------------------------------------------------------------
extern "C" void kernel_launch(void* const* d_in, const int* in_sizes, int n_in,
                              void* d_out, int out_size, void* d_ws, size_t ws_size,
                              hipStream_t stream)
{
    const float* emb   = (const float*)d_in[0];
    const float* W_wr  = (const float*)d_in[1];
    const float* b_wr  = (const float*)d_in[2];
    const float* W_qr  = (const float*)d_in[3];
    const float* b_qr  = (const float*)d_in[4];
    const float* W_out = (const float*)d_in[5];
    const float* b_out = (const float*)d_in[6];
    float* out = (float*)d_out;

    char* ws = (char*)d_ws;
    __hip_bfloat16* embb = (__hip_bfloat16*)(ws);                         // 0..64MB (dead after gemm1)
    __hip_bfloat16* rbuf = (__hip_bfloat16*)(ws);                         // 0..32MB (aliases dead embb)
    __hip_bfloat16* wvq  = (__hip_bfloat16*)(ws + (((size_t)64) << 20));  // 64..128MB
    __hip_bfloat16* wvt  = (__hip_bfloat16*)(ws + (((size_t)128) << 20)); // 128..160MB
    __hip_bfloat16* wcat = (__hip_bfloat16*)(ws + (((size_t)160) << 20)); // 2MB
    __hip_bfloat16* wout = (__hip_bfloat16*)(ws + (((size_t)162) << 20)); // 1MB
    float*          bcat = (float*)        (ws + (((size_t)163) << 20));  // 4KB

    prep<<<dim3(38913), dim3(256), 0, stream>>>(
        (const float4*)emb, (ushort4*)embb,
        W_wr, W_qr, W_out, b_wr, b_qr, wcat, wout, bcat);

    // WVQ = embb @ wcat^T + bcat (M=32768,N=1024,K=1024), bf16 out + WVT fused
    gemm256<true, true><<<dim3(512), dim3(512), 0, stream>>>(
        embb, EMB, wcat, EMB, bcat, (void*)wvq, 1024, wvt, EMB, 4);

    attn_mfma<<<dim3(MROWS / 64), dim3(256), 0, stream>>>(wvq, wvt, rbuf);

    // out = rbuf @ wout^T + b_out  (M=32768, N=1024, K=512), f32 out
    gemm256<false, false><<<dim3(512), dim3(512), 0, stream>>>(
        rbuf, DM, wout, DM, b_out, (void*)out, EMB, nullptr, DM, 4);
}

// Round 15
// 242.483 us; speedup vs baseline: 1.0183x; 1.0183x over previous
//
#include <hip/hip_runtime.h>
#include <hip/hip_bf16.h>
#include <math.h>

// HashMemory: B=8, S=4096, E=1024, Dm=512, M=64 slots.
// memory at step t == write_vals of tokens [t-64, t-1]  => window-64 attention.
// Pipeline: prep; WVQ = embb @ [W_write|W_query] (gemm_k64, fused WVT);
// attention; out = R @ W_out (gemm_k32).
// r15: per-GEMM best-of: GEMM1 = r12 structure (BK=64, 128KB, deep per-tile
// compute: best measured 82us at K=1024); GEMM2 = r14 structure (BK=32,
// 64KB, 2 blocks/CU: measured -8us at K=512 where short-K pipeline never
// amortizes a 1-block lockstep).

#define BATCH   8
#define S_LEN   4096
#define EMB     1024
#define DM      512
#define MROWS   (BATCH * S_LEN)          // 32768
#define SCALE_F 0.04419417382415922f     // 512^-0.5

typedef __attribute__((ext_vector_type(4))) float f32x4;
typedef __attribute__((ext_vector_type(8))) short short8;

__device__ __forceinline__ unsigned short f2bf(float f) {
    __hip_bfloat16 h = __float2bfloat16(f);
    return *reinterpret_cast<unsigned short*>(&h);
}

// ---------------------------------------------------------------------------
// Fused prep: emb f32->bf16 cast (blocks 0..32767), W_wr/W_qr/W_out
// transpose+cast (blocks 32768..38911), bias concat (block 38912).
// ---------------------------------------------------------------------------
__global__ __launch_bounds__(256) void prep(
    const float4* __restrict__ emb4, ushort4* __restrict__ embb4,
    const float* __restrict__ W_wr, const float* __restrict__ W_qr,
    const float* __restrict__ W_out,
    const float* __restrict__ b_wr, const float* __restrict__ b_qr,
    __hip_bfloat16* __restrict__ wcat, __hip_bfloat16* __restrict__ wout,
    float* __restrict__ bcat)
{
    const int bx = blockIdx.x;
    if (bx < 32768) {                              // emb cast: 8M float4
        int id = bx * 256 + threadIdx.x;
        float4 v = emb4[id];
        ushort4 o;
        o.x = f2bf(v.x); o.y = f2bf(v.y); o.z = f2bf(v.z); o.w = f2bf(v.w);
        embb4[id] = o;
    } else if (bx < 32768 + 2048) {                // wcat[0:512][1024] = W_wr^T
        int id = (bx - 32768) * 256 + threadIdx.x;
        int n = id >> 10, k = id & 1023;
        wcat[id] = __float2bfloat16(W_wr[k * 512 + n]);
    } else if (bx < 32768 + 4096) {                // wcat[512:1024][1024] = W_qr^T
        int id = (bx - 32768 - 2048) * 256 + threadIdx.x;
        int n = id >> 10, k = id & 1023;
        wcat[(size_t)DM * EMB + id] = __float2bfloat16(W_qr[k * 512 + n]);
    } else if (bx < 32768 + 6144) {                // wout[1024][512] = W_out^T
        int id = (bx - 32768 - 4096) * 256 + threadIdx.x;
        int n = id >> 9, k = id & 511;
        wout[id] = __float2bfloat16(W_out[k * 1024 + n]);
    } else {                                       // bias concat
        int i = threadIdx.x;
#pragma unroll
        for (int r = 0; r < 4; ++r, i += 256)
            bcat[i] = (i < 512) ? b_wr[i] : b_qr[i - 512];
    }
}

// ---------------------------------------------------------------------------
// GEMM1 kernel (r12-exact): 256x256 tile, BK=64, 8 waves, 128KB LDS.
// B-frags once/tile in regs, A-frags once per mh. Fused WVT epilogue.
// ---------------------------------------------------------------------------
template<bool BF16OUT, bool TRANSLO>
__global__ __launch_bounds__(512, 2) void gemm_k64(
    const __hip_bfloat16* __restrict__ A, int lda,
    const __hip_bfloat16* __restrict__ Bt, int ldb,
    const float* __restrict__ bias,
    void* __restrict__ Cv, int ldc,
    __hip_bfloat16* __restrict__ wvtp,
    int K, int nbx)
{
    __shared__ __align__(16) char smem[131072];

    const int nwg = gridDim.x;
    const int bid = blockIdx.x;
    const int cpx = nwg >> 3;
    const int swz = (bid & 7) * cpx + (bid >> 3);
    const int bm0 = (swz / nbx) << 8;
    const int bn0 = (swz % nbx) << 8;

    const int tid  = threadIdx.x;
    const int lane = tid & 63;
    const int w    = tid >> 6;
    const int wm   = w >> 2, wn = w & 3;
    const int l15  = lane & 15, lhi = lane >> 4;
    const int nt   = K >> 6;

    const int r64 = tid >> 3;
    const int cg8 = ((tid & 7) ^ (r64 & 7)) << 3;

    auto stage_tile = [&](int buf, int kt) {
#pragma unroll
        for (int h = 0; h < 4; ++h) {
            const int isB = h >> 1, hh = h & 1;
            const __hip_bfloat16* G = isB ? Bt : A;
            const int ldg = isB ? ldb : lda;
            const int rb  = (isB ? bn0 : bm0) + hh * 128;
#pragma unroll
            for (int i = 0; i < 2; ++i) {
                const __hip_bfloat16* g =
                    G + (size_t)(rb + i * 64 + r64) * ldg + kt + cg8;
                char* l = smem + buf * 65536 + isB * 32768 + hh * 16384
                          + i * 8192 + w * 1024;
                __builtin_amdgcn_global_load_lds(
                    (const __attribute__((address_space(1))) unsigned int*)g,
                    (__attribute__((address_space(3))) unsigned int*)l, 16, 0, 0);
            }
        }
    };

    f32x4 acc[8][4] = {};

    stage_tile(0, 0);
    __syncthreads();

    for (int t = 0; t < nt; ++t) {
        const int cur = t & 1;
        const bool pf = (t + 1 < nt);
        if (pf) stage_tile(cur ^ 1, (t + 1) << 6);

        const char* sA = smem + cur * 65536;
        const char* sB = sA + 32768;

        short8 bfv[2][2][2];
#pragma unroll
        for (int nh = 0; nh < 2; ++nh)
#pragma unroll
            for (int ni = 0; ni < 2; ++ni) {
                const int r = wn * 64 + nh * 32 + ni * 16 + l15;
#pragma unroll
                for (int kk = 0; kk < 2; ++kk) {
                    const int pc = (kk * 4 + lhi) ^ (r & 7);
                    bfv[nh][ni][kk] = *(const short8*)(sB + r * 128 + (pc << 4));
                }
            }

#pragma unroll
        for (int mh = 0; mh < 2; ++mh) {
            short8 af[4][2];
#pragma unroll
            for (int mi = 0; mi < 4; ++mi) {
                const int r = wm * 128 + mh * 64 + mi * 16 + l15;
#pragma unroll
                for (int kk = 0; kk < 2; ++kk) {
                    const int pc = (kk * 4 + lhi) ^ (r & 7);
                    af[mi][kk] = *(const short8*)(sA + r * 128 + (pc << 4));
                }
            }
#pragma unroll
            for (int nh = 0; nh < 2; ++nh)
#pragma unroll
                for (int mi = 0; mi < 4; ++mi)
#pragma unroll
                    for (int ni = 0; ni < 2; ++ni)
#pragma unroll
                        for (int kk = 0; kk < 2; ++kk)
                            acc[mh * 4 + mi][nh * 2 + ni] =
                                __builtin_amdgcn_mfma_f32_16x16x32_bf16(
                                    af[mi][kk], bfv[nh][ni][kk],
                                    acc[mh * 4 + mi][nh * 2 + ni], 0, 0, 0);
        }

        if (pf) __syncthreads();
    }

    float bv[4];
#pragma unroll
    for (int N = 0; N < 4; ++N)
        bv[N] = bias[bn0 + wn * 64 + (N >> 1) * 32 + (N & 1) * 16 + l15];

#pragma unroll
    for (int M = 0; M < 8; ++M) {
        const int row = bm0 + wm * 128 + (M >> 2) * 64 + (M & 3) * 16 + lhi * 4;
#pragma unroll
        for (int N = 0; N < 4; ++N) {
            const int col = bn0 + wn * 64 + (N >> 1) * 32 + (N & 1) * 16 + l15;
            float v[4];
#pragma unroll
            for (int reg = 0; reg < 4; ++reg)
                v[reg] = acc[M][N][reg] + bv[N];

#pragma unroll
            for (int reg = 0; reg < 4; ++reg) {
                if (BF16OUT)
                    ((__hip_bfloat16*)Cv)[(size_t)(row + reg) * ldc + col] =
                        __float2bfloat16(v[reg]);
                else
                    ((float*)Cv)[(size_t)(row + reg) * ldc + col] = v[reg];
            }
            if (TRANSLO && col < 512) {
                union { unsigned short s[4]; uint2 u; } tv;
#pragma unroll
                for (int reg = 0; reg < 4; ++reg) tv.s[reg] = f2bf(v[reg]);
                *(uint2*)((unsigned short*)wvtp
                          + (((size_t)((row >> 12) * 512 + col)) << 12)
                          + (row & 4095)) = tv.u;
            }
        }
    }
}

// ---------------------------------------------------------------------------
// GEMM2 kernel (r14-exact): 256x256 tile, BK=32, 64KB LDS => 2 blocks/CU.
// Best for short K (=512): co-resident block covers barrier drains.
// ---------------------------------------------------------------------------
template<bool BF16OUT>
__global__ __launch_bounds__(512, 2) void gemm_k32(
    const __hip_bfloat16* __restrict__ A, int lda,
    const __hip_bfloat16* __restrict__ Bt, int ldb,
    const float* __restrict__ bias,
    void* __restrict__ Cv, int ldc,
    int K, int nbx)
{
    __shared__ __align__(16) char smem[65536];

    const int nwg = gridDim.x;
    const int bid = blockIdx.x;
    const int cpx = nwg >> 3;
    const int swz = (bid & 7) * cpx + (bid >> 3);
    const int bm0 = (swz / nbx) << 8;
    const int bn0 = (swz % nbx) << 8;

    const int tid  = threadIdx.x;
    const int lane = tid & 63;
    const int w    = tid >> 6;
    const int wm   = w >> 2, wn = w & 3;
    const int l15  = lane & 15, lhi = lane >> 4;
    const int nt   = K >> 5;

    const int srow = tid >> 2;
    const int cg8  = ((tid & 3) ^ ((srow >> 1) & 3)) << 3;

    auto stage_tile = [&](int buf, int kt) {
#pragma unroll
        for (int h = 0; h < 4; ++h) {
            const int isB = h >> 1, rg = h & 1;
            const __hip_bfloat16* G = isB ? Bt : A;
            const int ldg = isB ? ldb : lda;
            const int rb  = (isB ? bn0 : bm0) + rg * 128;
            const __hip_bfloat16* g =
                G + (size_t)(rb + srow) * ldg + kt + cg8;
            char* l = smem + buf * 32768 + isB * 16384 + rg * 8192 + w * 1024;
            __builtin_amdgcn_global_load_lds(
                (const __attribute__((address_space(1))) unsigned int*)g,
                (__attribute__((address_space(3))) unsigned int*)l, 16, 0, 0);
        }
    };

    f32x4 acc[8][4] = {};

    stage_tile(0, 0);
    __syncthreads();

    for (int t = 0; t < nt; ++t) {
        const int cur = t & 1;
        const bool pf = (t + 1 < nt);
        if (pf) stage_tile(cur ^ 1, (t + 1) << 5);

        const char* sA = smem + cur * 32768;
        const char* sB = sA + 16384;

        short8 bfv[4];
#pragma unroll
        for (int n4 = 0; n4 < 4; ++n4) {
            const int r  = wn * 64 + n4 * 16 + l15;
            const int pc = lhi ^ ((r >> 1) & 3);
            bfv[n4] = *(const short8*)(sB + (r >> 7) * 8192
                                          + (r & 127) * 64 + (pc << 4));
        }

#pragma unroll
        for (int m8 = 0; m8 < 8; ++m8) {
            const int r  = wm * 128 + m8 * 16 + l15;
            const int pc = lhi ^ ((r >> 1) & 3);
            short8 af = *(const short8*)(sA + (r >> 7) * 8192
                                            + (r & 127) * 64 + (pc << 4));
#pragma unroll
            for (int n4 = 0; n4 < 4; ++n4)
                acc[m8][n4] = __builtin_amdgcn_mfma_f32_16x16x32_bf16(
                    af, bfv[n4], acc[m8][n4], 0, 0, 0);
        }

        if (pf) __syncthreads();
    }

    float bv[4];
#pragma unroll
    for (int N = 0; N < 4; ++N)
        bv[N] = bias[bn0 + wn * 64 + N * 16 + l15];

#pragma unroll
    for (int M = 0; M < 8; ++M) {
        const int row = bm0 + wm * 128 + M * 16 + lhi * 4;
#pragma unroll
        for (int N = 0; N < 4; ++N) {
            const int col = bn0 + wn * 64 + N * 16 + l15;
#pragma unroll
            for (int reg = 0; reg < 4; ++reg) {
                float v = acc[M][N][reg] + bv[N];
                if (BF16OUT)
                    ((__hip_bfloat16*)Cv)[(size_t)(row + reg) * ldc + col] =
                        __float2bfloat16(v);
                else
                    ((float*)Cv)[(size_t)(row + reg) * ldc + col] = v;
            }
        }
    }
}

// ---------------------------------------------------------------------------
// MFMA windowed attention. Block = 64 tokens, 4 waves, XCD-chunked swizzle.
// ---------------------------------------------------------------------------
__global__ __launch_bounds__(256) void attn_mfma(
    const __hip_bfloat16* __restrict__ WVQ,   // [32768][1024]: 0:512=WV, 512:=Q
    const __hip_bfloat16* __restrict__ WVT,   // [8][512][4096]
    __hip_bfloat16* __restrict__ R)           // [32768][512]
{
    __shared__ __align__(16) unsigned short p_lds[64][136];  // 17408 B

    const int blk0 = blockIdx.x;                 // 512 blocks, 512%8==0
    const int blk  = (blk0 & 7) * 64 + (blk0 >> 3);   // XCD-chunked (T1)
    const int b   = blk >> 6;
    const int t0  = (blk & 63) << 6;
    const int jmin = (t0 == 0) ? 64 : 0;
    const size_t bbase = (size_t)b << 12;
    const int tid  = threadIdx.x;
    const int lane = tid & 63;
    const int w    = tid >> 6;
    const int l15  = lane & 15;
    const int lhi  = lane >> 4;

    // ---- QK^T:  S[64][128] ----
    f32x4 acc[8] = {};
    const __hip_bfloat16* q0 =
        WVQ + ((bbase + t0 + w * 16 + l15) << 10) + 512 + lhi * 8;

    const __hip_bfloat16* brow[8];
#pragma unroll
    for (int nt = 0; nt < 8; ++nt) {
        int aj = t0 - 64 + nt * 16 + l15;
        if (aj < 0) aj = 0;                 // clamped; masked below
        brow[nt] = WVQ + ((bbase + aj) << 10) + lhi * 8;
    }

#pragma unroll 2
    for (int kt = 0; kt < 16; ++kt) {
        short8 qa = *(const short8*)(q0 + kt * 32);
#pragma unroll
        for (int nt = 0; nt < 8; ++nt) {
            short8 bv = *(const short8*)(brow[nt] + kt * 32);
            acc[nt] = __builtin_amdgcn_mfma_f32_16x16x32_bf16(qa, bv, acc[nt], 0, 0, 0);
        }
    }

    // ---- wave-local softmax ----
    float m4[4] = { -1e30f, -1e30f, -1e30f, -1e30f };
#pragma unroll
    for (int nt = 0; nt < 8; ++nt)
#pragma unroll
        for (int reg = 0; reg < 4; ++reg) {
            int i = w * 16 + lhi * 4 + reg;
            int j = nt * 16 + l15;
            bool valid = (j >= i) && (j <= i + 63) && (j >= jmin);
            float s = valid ? acc[nt][reg] * SCALE_F : -1e30f;
            acc[nt][reg] = s;
            m4[reg] = fmaxf(m4[reg], s);
        }
#pragma unroll
    for (int off = 8; off >= 1; off >>= 1)
#pragma unroll
        for (int reg = 0; reg < 4; ++reg)
            m4[reg] = fmaxf(m4[reg], __shfl_xor(m4[reg], off, 64));

    float sum4[4] = {};
#pragma unroll
    for (int nt = 0; nt < 8; ++nt)
#pragma unroll
        for (int reg = 0; reg < 4; ++reg) {
            float s = acc[nt][reg];
            float p = (s > -1e29f) ? __expf(s - m4[reg]) : 0.f;
            acc[nt][reg] = p;
            sum4[reg] += p;
        }
#pragma unroll
    for (int off = 8; off >= 1; off >>= 1)
#pragma unroll
        for (int reg = 0; reg < 4; ++reg)
            sum4[reg] += __shfl_xor(sum4[reg], off, 64);

    float rs4[4];
#pragma unroll
    for (int reg = 0; reg < 4; ++reg)
        rs4[reg] = (sum4[reg] > 0.f) ? 1.f / sum4[reg] : 0.f;

#pragma unroll
    for (int nt = 0; nt < 8; ++nt)
#pragma unroll
        for (int reg = 0; reg < 4; ++reg)
            p_lds[w * 16 + lhi * 4 + reg][nt * 16 + l15] =
                f2bf(acc[nt][reg] * rs4[reg]);

    __syncthreads();

    // ---- PV ----
    short8 pa[4];
#pragma unroll
    for (int kt = 0; kt < 4; ++kt)
        pa[kt] = *(const short8*)&p_lds[w * 16 + l15][kt * 32 + lhi * 8];

    int tclamp[4];
#pragma unroll
    for (int kt = 0; kt < 4; ++kt) {
        int ti = t0 - 64 + kt * 32 + lhi * 8;
        tclamp[kt] = ti < 0 ? 0 : ti;       // 8-chunks never straddle 0
    }

    const size_t vbase = (size_t)b * 512;
#pragma unroll 2
    for (int nt = 0; nt < 32; ++nt) {
        int d = nt * 16 + l15;
        f32x4 a = {};
#pragma unroll
        for (int kt = 0; kt < 4; ++kt) {
            short8 bv = *(const short8*)(WVT + ((vbase + d) << 12) + tclamp[kt]);
            a = __builtin_amdgcn_mfma_f32_16x16x32_bf16(pa[kt], bv, a, 0, 0, 0);
        }
        size_t rb = (bbase + t0 + w * 16 + lhi * 4) << 9;
#pragma unroll
        for (int reg = 0; reg < 4; ++reg)
            R[rb + ((size_t)reg << 9) + d] = __float2bfloat16(a[reg]);
    }
}

// ---------------------------------------------------------------------------
extern "C" void kernel_launch(void* const* d_in, const int* in_sizes, int n_in,
                              void* d_out, int out_size, void* d_ws, size_t ws_size,
                              hipStream_t stream)
{
    const float* emb   = (const float*)d_in[0];
    const float* W_wr  = (const float*)d_in[1];
    const float* b_wr  = (const float*)d_in[2];
    const float* W_qr  = (const float*)d_in[3];
    const float* b_qr  = (const float*)d_in[4];
    const float* W_out = (const float*)d_in[5];
    const float* b_out = (const float*)d_in[6];
    float* out = (float*)d_out;

    char* ws = (char*)d_ws;
    __hip_bfloat16* embb = (__hip_bfloat16*)(ws);                         // 0..64MB (dead after gemm1)
    __hip_bfloat16* rbuf = (__hip_bfloat16*)(ws);                         // 0..32MB (aliases dead embb)
    __hip_bfloat16* wvq  = (__hip_bfloat16*)(ws + (((size_t)64) << 20));  // 64..128MB
    __hip_bfloat16* wvt  = (__hip_bfloat16*)(ws + (((size_t)128) << 20)); // 128..160MB
    __hip_bfloat16* wcat = (__hip_bfloat16*)(ws + (((size_t)160) << 20)); // 2MB
    __hip_bfloat16* wout = (__hip_bfloat16*)(ws + (((size_t)162) << 20)); // 1MB
    float*          bcat = (float*)        (ws + (((size_t)163) << 20));  // 4KB

    prep<<<dim3(38913), dim3(256), 0, stream>>>(
        (const float4*)emb, (ushort4*)embb,
        W_wr, W_qr, W_out, b_wr, b_qr, wcat, wout, bcat);

    // WVQ = embb @ wcat^T + bcat (M=32768,N=1024,K=1024), bf16 out + WVT fused
    gemm_k64<true, true><<<dim3(512), dim3(512), 0, stream>>>(
        embb, EMB, wcat, EMB, bcat, (void*)wvq, 1024, wvt, EMB, 4);

    attn_mfma<<<dim3(MROWS / 64), dim3(256), 0, stream>>>(wvq, wvt, rbuf);

    // out = rbuf @ wout^T + b_out  (M=32768, N=1024, K=512), f32 out
    gemm_k32<false><<<dim3(512), dim3(512), 0, stream>>>(
        rbuf, DM, wout, DM, b_out, (void*)out, EMB, DM, 4);
}

// Round 16
// 222.148 us; speedup vs baseline: 1.1115x; 1.0915x over previous
//
#include <hip/hip_runtime.h>
#include <hip/hip_bf16.h>
#include <math.h>

// HashMemory: B=8, S=4096, E=1024, Dm=512, M=64 slots.
// memory at step t == write_vals of tokens [t-64, t-1]  => window-64 attention.
// Pipeline: prep; WVQ = embb @ [W_write|W_query] (gemm_k64, fused WVT);
// attention (QBLK=32, 2-wave blocks, r16); out = R @ W_out (gemm_k64).
// r16: GEMM2 reverted to r12-exact BK=64 (r15's BK=32 was noise-fit);
// attn split into 1024 light blocks (32 tokens, 96-row frame) for CU
// balance + latency hiding. jmin = max(0, 64-t0).

#define BATCH   8
#define S_LEN   4096
#define EMB     1024
#define DM      512
#define MROWS   (BATCH * S_LEN)          // 32768
#define SCALE_F 0.04419417382415922f     // 512^-0.5

typedef __attribute__((ext_vector_type(4))) float f32x4;
typedef __attribute__((ext_vector_type(8))) short short8;

__device__ __forceinline__ unsigned short f2bf(float f) {
    __hip_bfloat16 h = __float2bfloat16(f);
    return *reinterpret_cast<unsigned short*>(&h);
}

// ---------------------------------------------------------------------------
// Fused prep: emb f32->bf16 cast (blocks 0..32767), W_wr/W_qr/W_out
// transpose+cast (blocks 32768..38911), bias concat (block 38912).
// ---------------------------------------------------------------------------
__global__ __launch_bounds__(256) void prep(
    const float4* __restrict__ emb4, ushort4* __restrict__ embb4,
    const float* __restrict__ W_wr, const float* __restrict__ W_qr,
    const float* __restrict__ W_out,
    const float* __restrict__ b_wr, const float* __restrict__ b_qr,
    __hip_bfloat16* __restrict__ wcat, __hip_bfloat16* __restrict__ wout,
    float* __restrict__ bcat)
{
    const int bx = blockIdx.x;
    if (bx < 32768) {                              // emb cast: 8M float4
        int id = bx * 256 + threadIdx.x;
        float4 v = emb4[id];
        ushort4 o;
        o.x = f2bf(v.x); o.y = f2bf(v.y); o.z = f2bf(v.z); o.w = f2bf(v.w);
        embb4[id] = o;
    } else if (bx < 32768 + 2048) {                // wcat[0:512][1024] = W_wr^T
        int id = (bx - 32768) * 256 + threadIdx.x;
        int n = id >> 10, k = id & 1023;
        wcat[id] = __float2bfloat16(W_wr[k * 512 + n]);
    } else if (bx < 32768 + 4096) {                // wcat[512:1024][1024] = W_qr^T
        int id = (bx - 32768 - 2048) * 256 + threadIdx.x;
        int n = id >> 10, k = id & 1023;
        wcat[(size_t)DM * EMB + id] = __float2bfloat16(W_qr[k * 512 + n]);
    } else if (bx < 32768 + 6144) {                // wout[1024][512] = W_out^T
        int id = (bx - 32768 - 4096) * 256 + threadIdx.x;
        int n = id >> 9, k = id & 511;
        wout[id] = __float2bfloat16(W_out[k * 1024 + n]);
    } else {                                       // bias concat
        int i = threadIdx.x;
#pragma unroll
        for (int r = 0; r < 4; ++r, i += 256)
            bcat[i] = (i < 512) ? b_wr[i] : b_qr[i - 512];
    }
}

// ---------------------------------------------------------------------------
// GEMM (r12-exact): 256x256 tile, BK=64, 8 waves, 128KB LDS.
// B-frags once/tile in regs, A-frags once per mh. Optional fused WVT epilogue.
// ---------------------------------------------------------------------------
template<bool BF16OUT, bool TRANSLO>
__global__ __launch_bounds__(512, 2) void gemm_k64(
    const __hip_bfloat16* __restrict__ A, int lda,
    const __hip_bfloat16* __restrict__ Bt, int ldb,
    const float* __restrict__ bias,
    void* __restrict__ Cv, int ldc,
    __hip_bfloat16* __restrict__ wvtp,
    int K, int nbx)
{
    __shared__ __align__(16) char smem[131072];

    const int nwg = gridDim.x;
    const int bid = blockIdx.x;
    const int cpx = nwg >> 3;
    const int swz = (bid & 7) * cpx + (bid >> 3);
    const int bm0 = (swz / nbx) << 8;
    const int bn0 = (swz % nbx) << 8;

    const int tid  = threadIdx.x;
    const int lane = tid & 63;
    const int w    = tid >> 6;
    const int wm   = w >> 2, wn = w & 3;
    const int l15  = lane & 15, lhi = lane >> 4;
    const int nt   = K >> 6;

    const int r64 = tid >> 3;
    const int cg8 = ((tid & 7) ^ (r64 & 7)) << 3;

    auto stage_tile = [&](int buf, int kt) {
#pragma unroll
        for (int h = 0; h < 4; ++h) {
            const int isB = h >> 1, hh = h & 1;
            const __hip_bfloat16* G = isB ? Bt : A;
            const int ldg = isB ? ldb : lda;
            const int rb  = (isB ? bn0 : bm0) + hh * 128;
#pragma unroll
            for (int i = 0; i < 2; ++i) {
                const __hip_bfloat16* g =
                    G + (size_t)(rb + i * 64 + r64) * ldg + kt + cg8;
                char* l = smem + buf * 65536 + isB * 32768 + hh * 16384
                          + i * 8192 + w * 1024;
                __builtin_amdgcn_global_load_lds(
                    (const __attribute__((address_space(1))) unsigned int*)g,
                    (__attribute__((address_space(3))) unsigned int*)l, 16, 0, 0);
            }
        }
    };

    f32x4 acc[8][4] = {};

    stage_tile(0, 0);
    __syncthreads();

    for (int t = 0; t < nt; ++t) {
        const int cur = t & 1;
        const bool pf = (t + 1 < nt);
        if (pf) stage_tile(cur ^ 1, (t + 1) << 6);

        const char* sA = smem + cur * 65536;
        const char* sB = sA + 32768;

        short8 bfv[2][2][2];
#pragma unroll
        for (int nh = 0; nh < 2; ++nh)
#pragma unroll
            for (int ni = 0; ni < 2; ++ni) {
                const int r = wn * 64 + nh * 32 + ni * 16 + l15;
#pragma unroll
                for (int kk = 0; kk < 2; ++kk) {
                    const int pc = (kk * 4 + lhi) ^ (r & 7);
                    bfv[nh][ni][kk] = *(const short8*)(sB + r * 128 + (pc << 4));
                }
            }

#pragma unroll
        for (int mh = 0; mh < 2; ++mh) {
            short8 af[4][2];
#pragma unroll
            for (int mi = 0; mi < 4; ++mi) {
                const int r = wm * 128 + mh * 64 + mi * 16 + l15;
#pragma unroll
                for (int kk = 0; kk < 2; ++kk) {
                    const int pc = (kk * 4 + lhi) ^ (r & 7);
                    af[mi][kk] = *(const short8*)(sA + r * 128 + (pc << 4));
                }
            }
#pragma unroll
            for (int nh = 0; nh < 2; ++nh)
#pragma unroll
                for (int mi = 0; mi < 4; ++mi)
#pragma unroll
                    for (int ni = 0; ni < 2; ++ni)
#pragma unroll
                        for (int kk = 0; kk < 2; ++kk)
                            acc[mh * 4 + mi][nh * 2 + ni] =
                                __builtin_amdgcn_mfma_f32_16x16x32_bf16(
                                    af[mi][kk], bfv[nh][ni][kk],
                                    acc[mh * 4 + mi][nh * 2 + ni], 0, 0, 0);
        }

        if (pf) __syncthreads();
    }

    float bv[4];
#pragma unroll
    for (int N = 0; N < 4; ++N)
        bv[N] = bias[bn0 + wn * 64 + (N >> 1) * 32 + (N & 1) * 16 + l15];

#pragma unroll
    for (int M = 0; M < 8; ++M) {
        const int row = bm0 + wm * 128 + (M >> 2) * 64 + (M & 3) * 16 + lhi * 4;
#pragma unroll
        for (int N = 0; N < 4; ++N) {
            const int col = bn0 + wn * 64 + (N >> 1) * 32 + (N & 1) * 16 + l15;
            float v[4];
#pragma unroll
            for (int reg = 0; reg < 4; ++reg)
                v[reg] = acc[M][N][reg] + bv[N];

#pragma unroll
            for (int reg = 0; reg < 4; ++reg) {
                if (BF16OUT)
                    ((__hip_bfloat16*)Cv)[(size_t)(row + reg) * ldc + col] =
                        __float2bfloat16(v[reg]);
                else
                    ((float*)Cv)[(size_t)(row + reg) * ldc + col] = v[reg];
            }
            if (TRANSLO && col < 512) {
                union { unsigned short s[4]; uint2 u; } tv;
#pragma unroll
                for (int reg = 0; reg < 4; ++reg) tv.s[reg] = f2bf(v[reg]);
                *(uint2*)((unsigned short*)wvtp
                          + (((size_t)((row >> 12) * 512 + col)) << 12)
                          + (row & 4095)) = tv.u;
            }
        }
    }
}

// ---------------------------------------------------------------------------
// MFMA windowed attention, QBLK=32: 2 waves/block, 1024 blocks.
// Frame = 96 rows [t0-64, t0+31]. jmin = max(0, 64-t0).
// ---------------------------------------------------------------------------
__global__ __launch_bounds__(128) void attn_mfma32(
    const __hip_bfloat16* __restrict__ WVQ,   // [32768][1024]: 0:512=WV, 512:=Q
    const __hip_bfloat16* __restrict__ WVT,   // [8][512][4096]
    __hip_bfloat16* __restrict__ R)           // [32768][512]
{
    __shared__ __align__(16) unsigned short p_lds[32][104];  // 6656 B

    const int blk0 = blockIdx.x;                 // 1024 blocks, %8==0
    const int blk  = (blk0 & 7) * 128 + (blk0 >> 3);  // XCD-chunked (T1)
    const int b   = blk >> 7;                    // 128 blocks per batch
    const int t0  = (blk & 127) << 5;
    const int jmin = (t0 >= 64) ? 0 : 64 - t0;
    const size_t bbase = (size_t)b << 12;
    const int tid  = threadIdx.x;
    const int lane = tid & 63;
    const int w    = tid >> 6;                   // 0..1
    const int l15  = lane & 15;
    const int lhi  = lane >> 4;

    // ---- QK^T: S[32][96] ----
    f32x4 acc[6] = {};
    const __hip_bfloat16* q0 =
        WVQ + ((bbase + t0 + w * 16 + l15) << 10) + 512 + lhi * 8;

    const __hip_bfloat16* brow[6];
#pragma unroll
    for (int nt = 0; nt < 6; ++nt) {
        int aj = t0 - 64 + nt * 16 + l15;
        if (aj < 0) aj = 0;                 // clamped; masked below
        brow[nt] = WVQ + ((bbase + aj) << 10) + lhi * 8;
    }

#pragma unroll 2
    for (int kt = 0; kt < 16; ++kt) {
        short8 qa = *(const short8*)(q0 + kt * 32);
#pragma unroll
        for (int nt = 0; nt < 6; ++nt) {
            short8 bv = *(const short8*)(brow[nt] + kt * 32);
            acc[nt] = __builtin_amdgcn_mfma_f32_16x16x32_bf16(qa, bv, acc[nt], 0, 0, 0);
        }
    }

    // ---- wave-local softmax (rows i = w*16 + lhi*4 + reg) ----
    float m4[4] = { -1e30f, -1e30f, -1e30f, -1e30f };
#pragma unroll
    for (int nt = 0; nt < 6; ++nt)
#pragma unroll
        for (int reg = 0; reg < 4; ++reg) {
            int i = w * 16 + lhi * 4 + reg;
            int j = nt * 16 + l15;
            bool valid = (j >= i) && (j <= i + 63) && (j >= jmin);
            float s = valid ? acc[nt][reg] * SCALE_F : -1e30f;
            acc[nt][reg] = s;
            m4[reg] = fmaxf(m4[reg], s);
        }
#pragma unroll
    for (int off = 8; off >= 1; off >>= 1)
#pragma unroll
        for (int reg = 0; reg < 4; ++reg)
            m4[reg] = fmaxf(m4[reg], __shfl_xor(m4[reg], off, 64));

    float sum4[4] = {};
#pragma unroll
    for (int nt = 0; nt < 6; ++nt)
#pragma unroll
        for (int reg = 0; reg < 4; ++reg) {
            float s = acc[nt][reg];
            float p = (s > -1e29f) ? __expf(s - m4[reg]) : 0.f;
            acc[nt][reg] = p;
            sum4[reg] += p;
        }
#pragma unroll
    for (int off = 8; off >= 1; off >>= 1)
#pragma unroll
        for (int reg = 0; reg < 4; ++reg)
            sum4[reg] += __shfl_xor(sum4[reg], off, 64);

    float rs4[4];
#pragma unroll
    for (int reg = 0; reg < 4; ++reg)
        rs4[reg] = (sum4[reg] > 0.f) ? 1.f / sum4[reg] : 0.f;

#pragma unroll
    for (int nt = 0; nt < 6; ++nt)
#pragma unroll
        for (int reg = 0; reg < 4; ++reg)
            p_lds[w * 16 + lhi * 4 + reg][nt * 16 + l15] =
                f2bf(acc[nt][reg] * rs4[reg]);

    __syncthreads();

    // ---- PV: K-span 96 (3 k-steps) ----
    short8 pa[3];
#pragma unroll
    for (int kt = 0; kt < 3; ++kt)
        pa[kt] = *(const short8*)&p_lds[w * 16 + l15][kt * 32 + lhi * 8];

    int tclamp[3];
#pragma unroll
    for (int kt = 0; kt < 3; ++kt) {
        int ti = t0 - 64 + kt * 32 + lhi * 8;
        tclamp[kt] = ti < 0 ? 0 : ti;       // 8-chunks never straddle 0
    }

    const size_t vbase = (size_t)b * 512;
#pragma unroll 2
    for (int nt = 0; nt < 32; ++nt) {
        int d = nt * 16 + l15;
        f32x4 a = {};
#pragma unroll
        for (int kt = 0; kt < 3; ++kt) {
            short8 bv = *(const short8*)(WVT + ((vbase + d) << 12) + tclamp[kt]);
            a = __builtin_amdgcn_mfma_f32_16x16x32_bf16(pa[kt], bv, a, 0, 0, 0);
        }
        size_t rb = (bbase + t0 + w * 16 + lhi * 4) << 9;
#pragma unroll
        for (int reg = 0; reg < 4; ++reg)
            R[rb + ((size_t)reg << 9) + d] = __float2bfloat16(a[reg]);
    }
}

// ---------------------------------------------------------------------------
extern "C" void kernel_launch(void* const* d_in, const int* in_sizes, int n_in,
                              void* d_out, int out_size, void* d_ws, size_t ws_size,
                              hipStream_t stream)
{
    const float* emb   = (const float*)d_in[0];
    const float* W_wr  = (const float*)d_in[1];
    const float* b_wr  = (const float*)d_in[2];
    const float* W_qr  = (const float*)d_in[3];
    const float* b_qr  = (const float*)d_in[4];
    const float* W_out = (const float*)d_in[5];
    const float* b_out = (const float*)d_in[6];
    float* out = (float*)d_out;

    char* ws = (char*)d_ws;
    __hip_bfloat16* embb = (__hip_bfloat16*)(ws);                         // 0..64MB (dead after gemm1)
    __hip_bfloat16* rbuf = (__hip_bfloat16*)(ws);                         // 0..32MB (aliases dead embb)
    __hip_bfloat16* wvq  = (__hip_bfloat16*)(ws + (((size_t)64) << 20));  // 64..128MB
    __hip_bfloat16* wvt  = (__hip_bfloat16*)(ws + (((size_t)128) << 20)); // 128..160MB
    __hip_bfloat16* wcat = (__hip_bfloat16*)(ws + (((size_t)160) << 20)); // 2MB
    __hip_bfloat16* wout = (__hip_bfloat16*)(ws + (((size_t)162) << 20)); // 1MB
    float*          bcat = (float*)        (ws + (((size_t)163) << 20));  // 4KB

    prep<<<dim3(38913), dim3(256), 0, stream>>>(
        (const float4*)emb, (ushort4*)embb,
        W_wr, W_qr, W_out, b_wr, b_qr, wcat, wout, bcat);

    // WVQ = embb @ wcat^T + bcat (M=32768,N=1024,K=1024), bf16 out + WVT fused
    gemm_k64<true, true><<<dim3(512), dim3(512), 0, stream>>>(
        embb, EMB, wcat, EMB, bcat, (void*)wvq, 1024, wvt, EMB, 4);

    attn_mfma32<<<dim3(MROWS / 32), dim3(128), 0, stream>>>(wvq, wvt, rbuf);

    // out = rbuf @ wout^T + b_out  (M=32768, N=1024, K=512), f32 out
    gemm_k64<false, false><<<dim3(512), dim3(512), 0, stream>>>(
        rbuf, DM, wout, DM, b_out, (void*)out, EMB, nullptr, DM, 4);
}

// Round 17
// 221.999 us; speedup vs baseline: 1.1123x; 1.0007x over previous
//
#include <hip/hip_runtime.h>
#include <hip/hip_bf16.h>
#include <math.h>

// HashMemory: B=8, S=4096, E=1024, Dm=512, M=64 slots.
// memory at step t == write_vals of tokens [t-64, t-1]  => window-64 attention.
// Pipeline: prep; WVQ = embb @ [W_write|W_query] (gemm_k64 fused WVT);
// attention (QBLK=32, r16); out = R @ W_out (gemm_k64).
// r17: GEMM K-loop -> faithful 4-phase-per-tile schedule: per phase
// {counted vmcnt (p0/p2 only) -> stage 2 regions of t+1 -> s_barrier ->
// ds_read phase fragments -> setprio(1) 16xMFMA setprio(0)}.
// FIFO per tile: B0,B1,B2,B3,A0,A2 | A1,A3  (a-low = regions 0,2).
// p0 waits vmcnt(2) [first 6 = all B + a-low]; p2 waits vmcnt(4)
// [tile's a-high landed, t+1's 4 B-loads stay in flight]; tail: vmcnt(0).
// Correctness: per-wave counted vmcnt BEFORE the barrier certifies all
// waves' oldest loads landed (identical issue patterns); stages target
// buf[cur^1] regions disjoint from all concurrent buf[cur] reads; barriers
// are collective so waves stay within one phase window.

#define BATCH   8
#define S_LEN   4096
#define EMB     1024
#define DM      512
#define MROWS   (BATCH * S_LEN)          // 32768
#define SCALE_F 0.04419417382415922f     // 512^-0.5

typedef __attribute__((ext_vector_type(4))) float f32x4;
typedef __attribute__((ext_vector_type(8))) short short8;

__device__ __forceinline__ unsigned short f2bf(float f) {
    __hip_bfloat16 h = __float2bfloat16(f);
    return *reinterpret_cast<unsigned short*>(&h);
}

// ---------------------------------------------------------------------------
// Fused prep: emb f32->bf16 cast (blocks 0..32767), W_wr/W_qr/W_out
// transpose+cast (blocks 32768..38911), bias concat (block 38912).
// ---------------------------------------------------------------------------
__global__ __launch_bounds__(256) void prep(
    const float4* __restrict__ emb4, ushort4* __restrict__ embb4,
    const float* __restrict__ W_wr, const float* __restrict__ W_qr,
    const float* __restrict__ W_out,
    const float* __restrict__ b_wr, const float* __restrict__ b_qr,
    __hip_bfloat16* __restrict__ wcat, __hip_bfloat16* __restrict__ wout,
    float* __restrict__ bcat)
{
    const int bx = blockIdx.x;
    if (bx < 32768) {                              // emb cast: 8M float4
        int id = bx * 256 + threadIdx.x;
        float4 v = emb4[id];
        ushort4 o;
        o.x = f2bf(v.x); o.y = f2bf(v.y); o.z = f2bf(v.z); o.w = f2bf(v.w);
        embb4[id] = o;
    } else if (bx < 32768 + 2048) {                // wcat[0:512][1024] = W_wr^T
        int id = (bx - 32768) * 256 + threadIdx.x;
        int n = id >> 10, k = id & 1023;
        wcat[id] = __float2bfloat16(W_wr[k * 512 + n]);
    } else if (bx < 32768 + 4096) {                // wcat[512:1024][1024] = W_qr^T
        int id = (bx - 32768 - 2048) * 256 + threadIdx.x;
        int n = id >> 10, k = id & 1023;
        wcat[(size_t)DM * EMB + id] = __float2bfloat16(W_qr[k * 512 + n]);
    } else if (bx < 32768 + 6144) {                // wout[1024][512] = W_out^T
        int id = (bx - 32768 - 4096) * 256 + threadIdx.x;
        int n = id >> 9, k = id & 511;
        wout[id] = __float2bfloat16(W_out[k * 1024 + n]);
    } else {                                       // bias concat
        int i = threadIdx.x;
#pragma unroll
        for (int r = 0; r < 4; ++r, i += 256)
            bcat[i] = (i < 512) ? b_wr[i] : b_qr[i - 512];
    }
}

// ---------------------------------------------------------------------------
// bf16 MFMA GEMM, 256x256 tile, BK=64, 8 waves (2x4), 128KB LDS,
// 4-phase counted-vmcnt schedule (see header comment).
// ---------------------------------------------------------------------------
template<bool BF16OUT, bool TRANSLO>
__global__ __launch_bounds__(512, 2) void gemm_k64(
    const __hip_bfloat16* __restrict__ A, int lda,
    const __hip_bfloat16* __restrict__ Bt, int ldb,
    const float* __restrict__ bias,
    void* __restrict__ Cv, int ldc,
    __hip_bfloat16* __restrict__ wvtp,
    int K, int nbx)
{
    __shared__ __align__(16) char smem[131072];

    const int nwg = gridDim.x;
    const int bid = blockIdx.x;
    const int cpx = nwg >> 3;
    const int swz = (bid & 7) * cpx + (bid >> 3);
    const int bm0 = (swz / nbx) << 8;
    const int bn0 = (swz % nbx) << 8;

    const int tid  = threadIdx.x;
    const int lane = tid & 63;
    const int w    = tid >> 6;
    const int wm   = w >> 2, wn = w & 3;
    const int l15  = lane & 15, lhi = lane >> 4;
    const int nt   = K >> 6;

    // staging: thread owns linear LDS slot tid*16 per 8KB region (64 rows x
    // 64 cols): row-in-region = tid>>3, phys chunk = tid&7,
    // source chunk = (tid&7)^(row&7) (inverse swizzle).
    const int r64 = tid >> 3;
    const int cg8 = ((tid & 7) ^ (r64 & 7)) << 3;

    auto stageA = [&](int buf, int kt, int r) {  // A region r: rows r*64..+63
        const __hip_bfloat16* g =
            A + (size_t)(bm0 + r * 64 + r64) * lda + kt + cg8;
        char* l = smem + buf * 65536 + r * 8192 + w * 1024;
        __builtin_amdgcn_global_load_lds(
            (const __attribute__((address_space(1))) unsigned int*)g,
            (__attribute__((address_space(3))) unsigned int*)l, 16, 0, 0);
    };
    auto stageB = [&](int buf, int kt, int r) {
        const __hip_bfloat16* g =
            Bt + (size_t)(bn0 + r * 64 + r64) * ldb + kt + cg8;
        char* l = smem + buf * 65536 + 32768 + r * 8192 + w * 1024;
        __builtin_amdgcn_global_load_lds(
            (const __attribute__((address_space(1))) unsigned int*)g,
            (__attribute__((address_space(3))) unsigned int*)l, 16, 0, 0);
    };

    f32x4 acc[8][4] = {};   // [mh*4+mi][nh*2+ni]

    // ---- prologue: tile 0, FIFO B0 B1 B2 B3 A0 A2 | A1 A3 ----
    stageB(0, 0, 0); stageB(0, 0, 1); stageB(0, 0, 2); stageB(0, 0, 3);
    stageA(0, 0, 0); stageA(0, 0, 2); stageA(0, 0, 1); stageA(0, 0, 3);

    for (int t = 0; t < nt; ++t) {
        const int cur = t & 1;
        const bool pf = (t + 1 < nt);
        const int kt1 = (t + 1) << 6;
        const char* sA = smem + cur * 65536;
        const char* sB = sA + 32768;

        short8 aF[4][2], b0[2][2], b1[2][2];

        // ========== P0: q(0,0) — needs all B + a-low (oldest 6) ==========
        asm volatile("s_waitcnt vmcnt(2)" ::: "memory");
        if (pf) { stageB(cur ^ 1, kt1, 0); stageB(cur ^ 1, kt1, 1); }
        asm volatile("s_barrier" ::: "memory");
#pragma unroll
        for (int ni = 0; ni < 2; ++ni) {
            const int r = wn * 64 + ni * 16 + l15;
#pragma unroll
            for (int kk = 0; kk < 2; ++kk) {
                const int pc = (kk * 4 + lhi) ^ (r & 7);
                b0[ni][kk] = *(const short8*)(sB + r * 128 + (pc << 4));
            }
        }
#pragma unroll
        for (int mi = 0; mi < 4; ++mi) {
            const int r = wm * 128 + mi * 16 + l15;          // a-low
#pragma unroll
            for (int kk = 0; kk < 2; ++kk) {
                const int pc = (kk * 4 + lhi) ^ (r & 7);
                aF[mi][kk] = *(const short8*)(sA + r * 128 + (pc << 4));
            }
        }
        __builtin_amdgcn_s_setprio(1);
#pragma unroll
        for (int mi = 0; mi < 4; ++mi)
#pragma unroll
            for (int ni = 0; ni < 2; ++ni)
#pragma unroll
                for (int kk = 0; kk < 2; ++kk)
                    acc[mi][ni] = __builtin_amdgcn_mfma_f32_16x16x32_bf16(
                        aF[mi][kk], b0[ni][kk], acc[mi][ni], 0, 0, 0);
        __builtin_amdgcn_s_setprio(0);

        // ========== P1: q(0,1) — b1 already valid since P0 ==========
        if (pf) { stageB(cur ^ 1, kt1, 2); stageB(cur ^ 1, kt1, 3); }
        asm volatile("s_barrier" ::: "memory");
#pragma unroll
        for (int ni = 0; ni < 2; ++ni) {
            const int r = wn * 64 + 32 + ni * 16 + l15;
#pragma unroll
            for (int kk = 0; kk < 2; ++kk) {
                const int pc = (kk * 4 + lhi) ^ (r & 7);
                b1[ni][kk] = *(const short8*)(sB + r * 128 + (pc << 4));
            }
        }
        __builtin_amdgcn_s_setprio(1);
#pragma unroll
        for (int mi = 0; mi < 4; ++mi)
#pragma unroll
            for (int ni = 0; ni < 2; ++ni)
#pragma unroll
                for (int kk = 0; kk < 2; ++kk)
                    acc[mi][2 + ni] = __builtin_amdgcn_mfma_f32_16x16x32_bf16(
                        aF[mi][kk], b1[ni][kk], acc[mi][2 + ni], 0, 0, 0);
        __builtin_amdgcn_s_setprio(0);

        // ========== P2: q(1,0) — needs a-high (tile's last 2 loads) ======
        if (pf) {
            asm volatile("s_waitcnt vmcnt(4)" ::: "memory");  // t+1's B fly
            stageA(cur ^ 1, kt1, 0); stageA(cur ^ 1, kt1, 2);
        } else {
            asm volatile("s_waitcnt vmcnt(0)" ::: "memory");  // tail drain
        }
        asm volatile("s_barrier" ::: "memory");
#pragma unroll
        for (int mi = 0; mi < 4; ++mi) {
            const int r = wm * 128 + 64 + mi * 16 + l15;     // a-high
#pragma unroll
            for (int kk = 0; kk < 2; ++kk) {
                const int pc = (kk * 4 + lhi) ^ (r & 7);
                aF[mi][kk] = *(const short8*)(sA + r * 128 + (pc << 4));
            }
        }
        __builtin_amdgcn_s_setprio(1);
#pragma unroll
        for (int mi = 0; mi < 4; ++mi)
#pragma unroll
            for (int ni = 0; ni < 2; ++ni)
#pragma unroll
                for (int kk = 0; kk < 2; ++kk)
                    acc[4 + mi][ni] = __builtin_amdgcn_mfma_f32_16x16x32_bf16(
                        aF[mi][kk], b0[ni][kk], acc[4 + mi][ni], 0, 0, 0);
        __builtin_amdgcn_s_setprio(0);

        // ========== P3: q(1,1) — register-only ==========
        if (pf) { stageA(cur ^ 1, kt1, 1); stageA(cur ^ 1, kt1, 3); }
        asm volatile("s_barrier" ::: "memory");
        __builtin_amdgcn_s_setprio(1);
#pragma unroll
        for (int mi = 0; mi < 4; ++mi)
#pragma unroll
            for (int ni = 0; ni < 2; ++ni)
#pragma unroll
                for (int kk = 0; kk < 2; ++kk)
                    acc[4 + mi][2 + ni] = __builtin_amdgcn_mfma_f32_16x16x32_bf16(
                        aF[mi][kk], b1[ni][kk], acc[4 + mi][2 + ni], 0, 0, 0);
        __builtin_amdgcn_s_setprio(0);
    }

    // ---- epilogue (r12-exact mapping) ----
    float bv[4];
#pragma unroll
    for (int N = 0; N < 4; ++N)
        bv[N] = bias[bn0 + wn * 64 + (N >> 1) * 32 + (N & 1) * 16 + l15];

#pragma unroll
    for (int M = 0; M < 8; ++M) {
        const int row = bm0 + wm * 128 + (M >> 2) * 64 + (M & 3) * 16 + lhi * 4;
#pragma unroll
        for (int N = 0; N < 4; ++N) {
            const int col = bn0 + wn * 64 + (N >> 1) * 32 + (N & 1) * 16 + l15;
            float v[4];
#pragma unroll
            for (int reg = 0; reg < 4; ++reg)
                v[reg] = acc[M][N][reg] + bv[N];

#pragma unroll
            for (int reg = 0; reg < 4; ++reg) {
                if (BF16OUT)
                    ((__hip_bfloat16*)Cv)[(size_t)(row + reg) * ldc + col] =
                        __float2bfloat16(v[reg]);
                else
                    ((float*)Cv)[(size_t)(row + reg) * ldc + col] = v[reg];
            }
            if (TRANSLO && col < 512) {
                union { unsigned short s[4]; uint2 u; } tv;
#pragma unroll
                for (int reg = 0; reg < 4; ++reg) tv.s[reg] = f2bf(v[reg]);
                *(uint2*)((unsigned short*)wvtp
                          + (((size_t)((row >> 12) * 512 + col)) << 12)
                          + (row & 4095)) = tv.u;
            }
        }
    }
}

// ---------------------------------------------------------------------------
// MFMA windowed attention, QBLK=32: 2 waves/block, 1024 blocks (r16-exact).
// ---------------------------------------------------------------------------
__global__ __launch_bounds__(128) void attn_mfma32(
    const __hip_bfloat16* __restrict__ WVQ,   // [32768][1024]: 0:512=WV, 512:=Q
    const __hip_bfloat16* __restrict__ WVT,   // [8][512][4096]
    __hip_bfloat16* __restrict__ R)           // [32768][512]
{
    __shared__ __align__(16) unsigned short p_lds[32][104];  // 6656 B

    const int blk0 = blockIdx.x;                 // 1024 blocks, %8==0
    const int blk  = (blk0 & 7) * 128 + (blk0 >> 3);  // XCD-chunked (T1)
    const int b   = blk >> 7;                    // 128 blocks per batch
    const int t0  = (blk & 127) << 5;
    const int jmin = (t0 >= 64) ? 0 : 64 - t0;
    const size_t bbase = (size_t)b << 12;
    const int tid  = threadIdx.x;
    const int lane = tid & 63;
    const int w    = tid >> 6;                   // 0..1
    const int l15  = lane & 15;
    const int lhi  = lane >> 4;

    // ---- QK^T: S[32][96] ----
    f32x4 acc[6] = {};
    const __hip_bfloat16* q0 =
        WVQ + ((bbase + t0 + w * 16 + l15) << 10) + 512 + lhi * 8;

    const __hip_bfloat16* brow[6];
#pragma unroll
    for (int nt = 0; nt < 6; ++nt) {
        int aj = t0 - 64 + nt * 16 + l15;
        if (aj < 0) aj = 0;                 // clamped; masked below
        brow[nt] = WVQ + ((bbase + aj) << 10) + lhi * 8;
    }

#pragma unroll 2
    for (int kt = 0; kt < 16; ++kt) {
        short8 qa = *(const short8*)(q0 + kt * 32);
#pragma unroll
        for (int nt = 0; nt < 6; ++nt) {
            short8 bv = *(const short8*)(brow[nt] + kt * 32);
            acc[nt] = __builtin_amdgcn_mfma_f32_16x16x32_bf16(qa, bv, acc[nt], 0, 0, 0);
        }
    }

    // ---- wave-local softmax (rows i = w*16 + lhi*4 + reg) ----
    float m4[4] = { -1e30f, -1e30f, -1e30f, -1e30f };
#pragma unroll
    for (int nt = 0; nt < 6; ++nt)
#pragma unroll
        for (int reg = 0; reg < 4; ++reg) {
            int i = w * 16 + lhi * 4 + reg;
            int j = nt * 16 + l15;
            bool valid = (j >= i) && (j <= i + 63) && (j >= jmin);
            float s = valid ? acc[nt][reg] * SCALE_F : -1e30f;
            acc[nt][reg] = s;
            m4[reg] = fmaxf(m4[reg], s);
        }
#pragma unroll
    for (int off = 8; off >= 1; off >>= 1)
#pragma unroll
        for (int reg = 0; reg < 4; ++reg)
            m4[reg] = fmaxf(m4[reg], __shfl_xor(m4[reg], off, 64));

    float sum4[4] = {};
#pragma unroll
    for (int nt = 0; nt < 6; ++nt)
#pragma unroll
        for (int reg = 0; reg < 4; ++reg) {
            float s = acc[nt][reg];
            float p = (s > -1e29f) ? __expf(s - m4[reg]) : 0.f;
            acc[nt][reg] = p;
            sum4[reg] += p;
        }
#pragma unroll
    for (int off = 8; off >= 1; off >>= 1)
#pragma unroll
        for (int reg = 0; reg < 4; ++reg)
            sum4[reg] += __shfl_xor(sum4[reg], off, 64);

    float rs4[4];
#pragma unroll
    for (int reg = 0; reg < 4; ++reg)
        rs4[reg] = (sum4[reg] > 0.f) ? 1.f / sum4[reg] : 0.f;

#pragma unroll
    for (int nt = 0; nt < 6; ++nt)
#pragma unroll
        for (int reg = 0; reg < 4; ++reg)
            p_lds[w * 16 + lhi * 4 + reg][nt * 16 + l15] =
                f2bf(acc[nt][reg] * rs4[reg]);

    __syncthreads();

    // ---- PV: K-span 96 (3 k-steps) ----
    short8 pa[3];
#pragma unroll
    for (int kt = 0; kt < 3; ++kt)
        pa[kt] = *(const short8*)&p_lds[w * 16 + l15][kt * 32 + lhi * 8];

    int tclamp[3];
#pragma unroll
    for (int kt = 0; kt < 3; ++kt) {
        int ti = t0 - 64 + kt * 32 + lhi * 8;
        tclamp[kt] = ti < 0 ? 0 : ti;       // 8-chunks never straddle 0
    }

    const size_t vbase = (size_t)b * 512;
#pragma unroll 2
    for (int nt = 0; nt < 32; ++nt) {
        int d = nt * 16 + l15;
        f32x4 a = {};
#pragma unroll
        for (int kt = 0; kt < 3; ++kt) {
            short8 bv = *(const short8*)(WVT + ((vbase + d) << 12) + tclamp[kt]);
            a = __builtin_amdgcn_mfma_f32_16x16x32_bf16(pa[kt], bv, a, 0, 0, 0);
        }
        size_t rb = (bbase + t0 + w * 16 + lhi * 4) << 9;
#pragma unroll
        for (int reg = 0; reg < 4; ++reg)
            R[rb + ((size_t)reg << 9) + d] = __float2bfloat16(a[reg]);
    }
}

// ---------------------------------------------------------------------------
extern "C" void kernel_launch(void* const* d_in, const int* in_sizes, int n_in,
                              void* d_out, int out_size, void* d_ws, size_t ws_size,
                              hipStream_t stream)
{
    const float* emb   = (const float*)d_in[0];
    const float* W_wr  = (const float*)d_in[1];
    const float* b_wr  = (const float*)d_in[2];
    const float* W_qr  = (const float*)d_in[3];
    const float* b_qr  = (const float*)d_in[4];
    const float* W_out = (const float*)d_in[5];
    const float* b_out = (const float*)d_in[6];
    float* out = (float*)d_out;

    char* ws = (char*)d_ws;
    __hip_bfloat16* embb = (__hip_bfloat16*)(ws);                         // 0..64MB (dead after gemm1)
    __hip_bfloat16* rbuf = (__hip_bfloat16*)(ws);                         // 0..32MB (aliases dead embb)
    __hip_bfloat16* wvq  = (__hip_bfloat16*)(ws + (((size_t)64) << 20));  // 64..128MB
    __hip_bfloat16* wvt  = (__hip_bfloat16*)(ws + (((size_t)128) << 20)); // 128..160MB
    __hip_bfloat16* wcat = (__hip_bfloat16*)(ws + (((size_t)160) << 20)); // 2MB
    __hip_bfloat16* wout = (__hip_bfloat16*)(ws + (((size_t)162) << 20)); // 1MB
    float*          bcat = (float*)        (ws + (((size_t)163) << 20));  // 4KB

    prep<<<dim3(38913), dim3(256), 0, stream>>>(
        (const float4*)emb, (ushort4*)embb,
        W_wr, W_qr, W_out, b_wr, b_qr, wcat, wout, bcat);

    // WVQ = embb @ wcat^T + bcat (M=32768,N=1024,K=1024), bf16 out + WVT fused
    gemm_k64<true, true><<<dim3(512), dim3(512), 0, stream>>>(
        embb, EMB, wcat, EMB, bcat, (void*)wvq, 1024, wvt, EMB, 4);

    attn_mfma32<<<dim3(MROWS / 32), dim3(128), 0, stream>>>(wvq, wvt, rbuf);

    // out = rbuf @ wout^T + b_out  (M=32768, N=1024, K=512), f32 out
    gemm_k64<false, false><<<dim3(512), dim3(512), 0, stream>>>(
        rbuf, DM, wout, DM, b_out, (void*)out, EMB, nullptr, DM, 4);
}